// Round 2
// baseline (318.994 us; speedup 1.0000x reference)
//
#include <hip/hip_runtime.h>
#include <hip/hip_bf16.h>
#include <stdint.h>

#define DEVI __device__ __forceinline__

typedef __attribute__((ext_vector_type(8))) __bf16 bf16x8;
typedef __attribute__((ext_vector_type(4))) float f32x4;
typedef __attribute__((ext_vector_type(4))) unsigned short us4;

DEVI unsigned short f2bf(float x) {
  union { float f; unsigned u; } v; v.f = x;
  unsigned r = v.u + 0x7FFFu + ((v.u >> 16) & 1u);
  return (unsigned short)(r >> 16);
}

DEVI f32x4 mfma16(bf16x8 a, bf16x8 b, f32x4 c) {
  return __builtin_amdgcn_mfma_f32_16x16x32_bf16(a, b, c, 0, 0, 0);
}

// Read one 16x32 A/B fragment from a row-major bf16 LDS tile.
// Layout (gfx950 16x16x32): elem e <-> k = 4*(lane>>4) + (e&3) + 16*(e>>2).
// Caller passes row = tile_row_base + (lane&15).
DEVI bf16x8 ld_frag(const unsigned short* tile, int row, int ld, int kbase, int lane) {
  const unsigned short* p = tile + row * ld + kbase + ((lane >> 4) << 2);
  union { bf16x8 f; us4 h[2]; } u;
  u.h[0] = *(const us4*)p;
  u.h[1] = *(const us4*)(p + 16);
  return u.f;
}

// ---------------- weight transpose + bf16 cast ----------------
// even z: u-matrix [1024][128] -> [128][1024]; odd z: v-matrix [128][1024] -> [1024][128]
struct TP { const float* in[8]; unsigned short* out[8]; };

__global__ __launch_bounds__(256) void wtrans(TP p) {
  const int z = blockIdx.y;
  const int K = (z & 1) ? 128 : 1024;
  const int N = (z & 1) ? 1024 : 128;
  const int i = blockIdx.x * 256 + threadIdx.x;  // grid covers exactly 131072
  const int k = i / N, n = i % N;
  p.out[z][(size_t)n * K + k] = f2bf(p.in[z][i]);
}

// ---------------- generic low-rank GEMM ----------------
// C[M,N] = (A[M,K] @ W[K,N] + bias) * oscale ; W passed pre-transposed bf16 [N][K]
struct GP {
  const void* A[3];
  const unsigned short* WT[3];
  const float* bias[3];
  void* C[3];
  float oscale[3];
};

template<bool ABF16, bool OBF16, bool BIAS>
__global__ __launch_bounds__(256)
void gemm_k(GP p, int M, int N, int K) {
  __shared__ unsigned short As[128][36];  // BM=128 x BK=32 (+4 pad)
  __shared__ unsigned short Ws[64][36];   // BN=64  x BK=32 (W^T rows = n)
  const int tid = threadIdx.x, lane = tid & 63, wid = tid >> 6;
  const int z = blockIdx.z;
  const int m0 = blockIdx.x * 128, n0 = blockIdx.y * 64;
  const int wm = (wid >> 1) * 64, wn = (wid & 1) * 32;
  f32x4 acc[4][2] = {};

  const int arow = tid >> 1, aseg = (tid & 1) * 16;
  const int wrow = tid >> 2, wseg = (tid & 3) * 8;
  const float* Af = (const float*)p.A[z];
  const unsigned short* Ab = (const unsigned short*)p.A[z];
  const unsigned short* Wt = p.WT[z];

  for (int k0 = 0; k0 < K; k0 += 32) {
    __syncthreads();
    {  // stage A tile 128x32 (cast fp32->bf16 if needed)
      union { uint4 u[2]; us4 h[4]; unsigned short s[16]; } t;
      if (ABF16) {
        const unsigned short* src = Ab + (size_t)(m0 + arow) * K + k0 + aseg;
        t.u[0] = *(const uint4*)src;
        t.u[1] = *(const uint4*)(src + 8);
      } else {
        const float* src = Af + (size_t)(m0 + arow) * K + k0 + aseg;
        #pragma unroll
        for (int j = 0; j < 16; j += 4) {
          float4 f = *(const float4*)(src + j);
          t.s[j] = f2bf(f.x); t.s[j + 1] = f2bf(f.y);
          t.s[j + 2] = f2bf(f.z); t.s[j + 3] = f2bf(f.w);
        }
      }
      us4* dst = (us4*)&As[arow][aseg];
      dst[0] = t.h[0]; dst[1] = t.h[1]; dst[2] = t.h[2]; dst[3] = t.h[3];
    }
    {  // stage W^T tile 64(n) x 32(k), already bf16
      union { uint4 u; us4 h[2]; } t;
      const unsigned short* src = Wt + (size_t)(n0 + wrow) * K + k0 + wseg;
      t.u = *(const uint4*)src;
      us4* dst = (us4*)&Ws[wrow][wseg];
      dst[0] = t.h[0]; dst[1] = t.h[1];
    }
    __syncthreads();

    bf16x8 af[4], wf[2];
    #pragma unroll
    for (int mi = 0; mi < 4; mi++)
      af[mi] = ld_frag(&As[0][0], wm + mi * 16 + (lane & 15), 36, 0, lane);
    #pragma unroll
    for (int ni = 0; ni < 2; ni++)
      wf[ni] = ld_frag(&Ws[0][0], wn + ni * 16 + (lane & 15), 36, 0, lane);
    #pragma unroll
    for (int mi = 0; mi < 4; mi++)
      #pragma unroll
      for (int ni = 0; ni < 2; ni++)
        acc[mi][ni] = mfma16(af[mi], wf[ni], acc[mi][ni]);
  }

  const float os = p.oscale[z];
  #pragma unroll
  for (int ni = 0; ni < 2; ni++) {
    const int col = n0 + wn + ni * 16 + (lane & 15);
    const float bv = BIAS ? p.bias[z][col] : 0.0f;
    #pragma unroll
    for (int mi = 0; mi < 4; mi++)
      #pragma unroll
      for (int r = 0; r < 4; r++) {
        const int row = m0 + wm + mi * 16 + ((lane >> 4) << 2) + r;
        float vv = (acc[mi][ni][r] + bv) * os;
        if (OBF16) ((unsigned short*)p.C[z])[(size_t)row * N + col] = f2bf(vv);
        else       ((float*)p.C[z])[(size_t)row * N + col] = vv;
      }
  }
}

// ---------------- flash attention ----------------
// qh (pre-scaled by 1/sqrt(hd)), kh, vh: [B*S][1024] bf16; ctx out same layout.
__global__ __launch_bounds__(256)
void attn_k(const unsigned short* __restrict__ qh, const unsigned short* __restrict__ kh,
            const unsigned short* __restrict__ vh, const int* __restrict__ mask,
            unsigned short* __restrict__ ctx) {
  const int S = 2048, DM = 1024;
  __shared__ unsigned short Ks[64][68];       // K tile: [kv][d]
  __shared__ unsigned short VTs[64][68];      // V^T tile: [d][kv]
  __shared__ unsigned short Ps[4][32][68];    // per-wave probs [qrow][kv]
  __shared__ float mk[64];                    // additive mask per kv col
  const int tid = threadIdx.x, lane = tid & 63, w = tid >> 6;
  const int b = blockIdx.z, h = blockIdx.y, q0 = blockIdx.x * 128;
  const int qbase = q0 + w * 32;

  // Q fragments held in registers for the whole kernel (32 rows x 64 d per wave)
  bf16x8 qf[2][2];
  #pragma unroll
  for (int mi = 0; mi < 2; mi++)
    #pragma unroll
    for (int kk = 0; kk < 2; kk++) {
      const unsigned short* p = qh + (size_t)(b * S + qbase + mi * 16 + (lane & 15)) * DM
                                + h * 64 + kk * 32 + ((lane >> 4) << 2);
      union { bf16x8 f; us4 h4[2]; } u;
      u.h4[0] = *(const us4*)p;
      u.h4[1] = *(const us4*)(p + 16);
      qf[mi][kk] = u.f;
    }

  float mrow[2][4], lrow[2][4];
  f32x4 acc[2][4] = {};
  #pragma unroll
  for (int mi = 0; mi < 2; mi++)
    #pragma unroll
    for (int r = 0; r < 4; r++) { mrow[mi][r] = -1e30f; lrow[mi][r] = 0.f; }

  const int srow = tid >> 2, sseg = (tid & 3) * 16;

  for (int kv0 = 0; kv0 < S; kv0 += 64) {
    __syncthreads();  // protect K/VT overwrite vs prev iteration's reads
    {
      union { uint4 u[2]; us4 h[4]; unsigned short s[16]; } tk, tv;
      const unsigned short* ksrc = kh + (size_t)(b * S + kv0 + srow) * DM + h * 64 + sseg;
      tk.u[0] = *(const uint4*)ksrc; tk.u[1] = *(const uint4*)(ksrc + 8);
      us4* kd = (us4*)&Ks[srow][sseg];
      kd[0] = tk.h[0]; kd[1] = tk.h[1]; kd[2] = tk.h[2]; kd[3] = tk.h[3];
      const unsigned short* vsrc = vh + (size_t)(b * S + kv0 + srow) * DM + h * 64 + sseg;
      tv.u[0] = *(const uint4*)vsrc; tv.u[1] = *(const uint4*)(vsrc + 8);
      #pragma unroll
      for (int j = 0; j < 16; j++) VTs[sseg + j][srow] = tv.s[j];
      if (tid < 64) mk[tid] = (mask[b * S + kv0 + tid] == 0) ? -1e9f : 0.0f;
    }
    __syncthreads();

    // S = Q K^T  (scale pre-folded into qh)
    f32x4 sc[2][4];
    #pragma unroll
    for (int ni = 0; ni < 4; ni++) {
      bf16x8 kf0 = ld_frag(&Ks[0][0], ni * 16 + (lane & 15), 68, 0, lane);
      bf16x8 kf1 = ld_frag(&Ks[0][0], ni * 16 + (lane & 15), 68, 32, lane);
      #pragma unroll
      for (int mi = 0; mi < 2; mi++) {
        f32x4 zz = {0.f, 0.f, 0.f, 0.f};
        zz = mfma16(qf[mi][0], kf0, zz);
        zz = mfma16(qf[mi][1], kf1, zz);
        sc[mi][ni] = zz;
      }
    }
    #pragma unroll
    for (int mi = 0; mi < 2; mi++)
      #pragma unroll
      for (int ni = 0; ni < 4; ni++) {
        float ma = mk[ni * 16 + (lane & 15)];
        sc[mi][ni] += ma;
      }

    // online softmax: rows owned as row = 4*(lane>>4)+r (+16*mi); cols across lane&15
    #pragma unroll
    for (int mi = 0; mi < 2; mi++)
      #pragma unroll
      for (int r = 0; r < 4; r++) {
        float tm = fmaxf(fmaxf(sc[mi][0][r], sc[mi][1][r]), fmaxf(sc[mi][2][r], sc[mi][3][r]));
        tm = fmaxf(tm, __shfl_xor(tm, 1));
        tm = fmaxf(tm, __shfl_xor(tm, 2));
        tm = fmaxf(tm, __shfl_xor(tm, 4));
        tm = fmaxf(tm, __shfl_xor(tm, 8));
        float mnew = fmaxf(mrow[mi][r], tm);
        float alpha = __expf(mrow[mi][r] - mnew);
        mrow[mi][r] = mnew;
        float rs = 0.f;
        #pragma unroll
        for (int ni = 0; ni < 4; ni++) {
          float e = __expf(sc[mi][ni][r] - mnew);
          sc[mi][ni][r] = e;
          rs += e;
        }
        rs += __shfl_xor(rs, 1);
        rs += __shfl_xor(rs, 2);
        rs += __shfl_xor(rs, 4);
        rs += __shfl_xor(rs, 8);
        lrow[mi][r] = lrow[mi][r] * alpha + rs;
        #pragma unroll
        for (int di = 0; di < 4; di++) acc[mi][di][r] *= alpha;
      }

    // write P (wave-private LDS region; same-wave RAW handled by lgkmcnt)
    #pragma unroll
    for (int mi = 0; mi < 2; mi++)
      #pragma unroll
      for (int ni = 0; ni < 4; ni++)
        #pragma unroll
        for (int r = 0; r < 4; r++)
          Ps[w][mi * 16 + ((lane >> 4) << 2) + r][ni * 16 + (lane & 15)] = f2bf(sc[mi][ni][r]);

    // O += P V
    #pragma unroll
    for (int kk = 0; kk < 2; kk++) {
      bf16x8 pa0 = ld_frag(&Ps[w][0][0], 0 * 16 + (lane & 15), 68, kk * 32, lane);
      bf16x8 pa1 = ld_frag(&Ps[w][0][0], 1 * 16 + (lane & 15), 68, kk * 32, lane);
      #pragma unroll
      for (int di = 0; di < 4; di++) {
        bf16x8 vb = ld_frag(&VTs[0][0], di * 16 + (lane & 15), 68, kk * 32, lane);
        acc[0][di] = mfma16(pa0, vb, acc[0][di]);
        acc[1][di] = mfma16(pa1, vb, acc[1][di]);
      }
    }
  }

  #pragma unroll
  for (int mi = 0; mi < 2; mi++)
    #pragma unroll
    for (int di = 0; di < 4; di++)
      #pragma unroll
      for (int r = 0; r < 4; r++) {
        const int row = qbase + mi * 16 + ((lane >> 4) << 2) + r;
        float o = acc[mi][di][r] / lrow[mi][r];
        ctx[(size_t)(b * S + row) * DM + h * 64 + di * 16 + (lane & 15)] = f2bf(o);
      }
}

// ---------------- launch ----------------
extern "C" void kernel_launch(void* const* d_in, const int* in_sizes, int n_in,
                              void* d_out, int out_size, void* d_ws, size_t ws_size,
                              hipStream_t stream) {
  const float* q = (const float*)d_in[0];
  const float* k = (const float*)d_in[1];
  const float* v = (const float*)d_in[2];
  const int* mask = (const int*)d_in[3];
  const float* wu[4] = {(const float*)d_in[4], (const float*)d_in[7],
                        (const float*)d_in[10], (const float*)d_in[13]};
  const float* wv[4] = {(const float*)d_in[5], (const float*)d_in[8],
                        (const float*)d_in[11], (const float*)d_in[14]};
  const float* wb[4] = {(const float*)d_in[6], (const float*)d_in[9],
                        (const float*)d_in[12], (const float*)d_in[15]};

  char* ws = (char*)d_ws;
  unsigned short* WT  = (unsigned short*)ws;                       // 8 * 131072 bf16
  unsigned short* T0  = (unsigned short*)(ws + 2097152);           // 4096x128 bf16
  unsigned short* T1  = T0 + 524288;
  unsigned short* T2  = T1 + 524288;
  unsigned short* QH  = (unsigned short*)(ws + 2097152 + 3145728); // 4096x1024 bf16
  unsigned short* KH  = QH + 4194304;
  unsigned short* VH  = KH + 4194304;
  unsigned short* CTX = VH + 4194304;                              // total ~37 MB

  TP tp;
  for (int i = 0; i < 4; i++) { tp.in[2 * i] = wu[i]; tp.in[2 * i + 1] = wv[i]; }
  for (int i = 0; i < 8; i++) tp.out[i] = WT + (size_t)i * 131072;
  wtrans<<<dim3(512, 8), 256, 0, stream>>>(tp);

  const float SCALE = 0.125f;  // 1/sqrt(64), folded into qh epilogue

  GP g1 = {};
  g1.A[0] = q; g1.A[1] = k; g1.A[2] = v;
  g1.WT[0] = tp.out[0]; g1.WT[1] = tp.out[2]; g1.WT[2] = tp.out[4];
  g1.C[0] = T0; g1.C[1] = T1; g1.C[2] = T2;
  g1.oscale[0] = g1.oscale[1] = g1.oscale[2] = 1.f;
  gemm_k<false, true, false><<<dim3(32, 2, 3), 256, 0, stream>>>(g1, 4096, 128, 1024);

  GP g2 = {};
  g2.A[0] = T0; g2.A[1] = T1; g2.A[2] = T2;
  g2.WT[0] = tp.out[1]; g2.WT[1] = tp.out[3]; g2.WT[2] = tp.out[5];
  g2.bias[0] = wb[0]; g2.bias[1] = wb[1]; g2.bias[2] = wb[2];
  g2.C[0] = QH; g2.C[1] = KH; g2.C[2] = VH;
  g2.oscale[0] = SCALE; g2.oscale[1] = 1.f; g2.oscale[2] = 1.f;
  gemm_k<true, true, true><<<dim3(32, 16, 3), 256, 0, stream>>>(g2, 4096, 1024, 128);

  attn_k<<<dim3(16, 16, 2), 256, 0, stream>>>(QH, KH, VH, mask, CTX);

  GP g3 = {};
  g3.A[0] = CTX; g3.WT[0] = tp.out[6]; g3.C[0] = T0; g3.oscale[0] = 1.f;
  gemm_k<true, true, false><<<dim3(32, 2, 1), 256, 0, stream>>>(g3, 4096, 128, 1024);

  GP g4 = {};
  g4.A[0] = T0; g4.WT[0] = tp.out[7]; g4.bias[0] = wb[3];
  g4.C[0] = d_out; g4.oscale[0] = 1.f;
  gemm_k<true, false, true><<<dim3(32, 16, 1), 256, 0, stream>>>(g4, 4096, 1024, 128);
}

// Round 3
// 269.343 us; speedup vs baseline: 1.1843x; 1.1843x over previous
//
#include <hip/hip_runtime.h>
#include <hip/hip_bf16.h>
#include <stdint.h>

#define DEVI __device__ __forceinline__

typedef __attribute__((ext_vector_type(8))) __bf16 bf16x8;
typedef __attribute__((ext_vector_type(4))) float f32x4;
typedef __attribute__((ext_vector_type(4))) unsigned short us4;

DEVI unsigned short f2bf(float x) {
  union { __bf16 b; unsigned short s; } u;
  u.b = (__bf16)x;  // hardware RNE cvt
  return u.s;
}

DEVI f32x4 mfma16(bf16x8 a, bf16x8 b, f32x4 c) {
  return __builtin_amdgcn_mfma_f32_16x16x32_bf16(a, b, c, 0, 0, 0);
}

// Read one 16x32 A/B fragment from a row-major bf16 LDS tile.
// Layout (gfx950 16x16x32): elem e <-> k = 4*(lane>>4) + (e&3) + 16*(e>>2).
// Caller passes row = tile_row_base + (lane&15).
DEVI bf16x8 ld_frag(const unsigned short* tile, int row, int ld, int kbase, int lane) {
  const unsigned short* p = tile + row * ld + kbase + ((lane >> 4) << 2);
  union { bf16x8 f; us4 h[2]; } u;
  u.h[0] = *(const us4*)p;
  u.h[1] = *(const us4*)(p + 16);
  return u.f;
}

// ---------------- weight transpose + bf16 cast (tiled, coalesced) ----------------
// even z: u-matrix in [1024][128]; odd z: v-matrix in [128][1024]. out = in^T (bf16).
struct TP { const float* in[8]; unsigned short* out[8]; };

__global__ __launch_bounds__(256) void wtrans2(TP p) {
  const int z = blockIdx.y;
  const int R = (z & 1) ? 128 : 1024;  // in rows
  const int C = (z & 1) ? 1024 : 128;  // in cols; out is [C][R]
  __shared__ unsigned short T[32][33];
  const int tilesC = C >> 5;
  const int tr0 = (blockIdx.x / tilesC) << 5;
  const int tc0 = (blockIdx.x % tilesC) << 5;
  const int tx = threadIdx.x & 31, ty = threadIdx.x >> 5;
  #pragma unroll
  for (int j = 0; j < 4; j++)
    T[ty + j * 8][tx] = f2bf(p.in[z][(size_t)(tr0 + ty + j * 8) * C + tc0 + tx]);
  __syncthreads();
  #pragma unroll
  for (int j = 0; j < 4; j++)
    p.out[z][(size_t)(tc0 + ty + j * 8) * R + tr0 + tx] = T[tx][ty + j * 8];
}

// ---------------- generic low-rank GEMM ----------------
// C[M,N] = (A[M,K] @ W[K,N] + bias) * oscale ; W passed pre-transposed bf16 [N][K]
struct GP {
  const void* A[3];
  const unsigned short* WT[3];
  const float* bias[3];
  void* C[3];
  float oscale[3];
};

template<bool ABF16, bool OBF16, bool BIAS>
__global__ __launch_bounds__(256)
void gemm_k(GP p, int M, int N, int K) {
  __shared__ unsigned short As[128][36];  // BM=128 x BK=32 (+4 pad)
  __shared__ unsigned short Ws[64][36];   // BN=64  x BK=32 (W^T rows = n)
  const int tid = threadIdx.x, lane = tid & 63, wid = tid >> 6;
  const int z = blockIdx.z;
  const int m0 = blockIdx.x * 128, n0 = blockIdx.y * 64;
  const int wm = (wid >> 1) * 64, wn = (wid & 1) * 32;
  f32x4 acc[4][2] = {};

  const int arow = tid >> 1, aseg = (tid & 1) * 16;
  const int wrow = tid >> 2, wseg = (tid & 3) * 8;
  const float* Af = (const float*)p.A[z];
  const unsigned short* Ab = (const unsigned short*)p.A[z];
  const unsigned short* Wt = p.WT[z];

  for (int k0 = 0; k0 < K; k0 += 32) {
    __syncthreads();
    {  // stage A tile 128x32 (cast fp32->bf16 if needed)
      union { uint4 u[2]; us4 h[4]; unsigned short s[16]; } t;
      if (ABF16) {
        const unsigned short* src = Ab + (size_t)(m0 + arow) * K + k0 + aseg;
        t.u[0] = *(const uint4*)src;
        t.u[1] = *(const uint4*)(src + 8);
      } else {
        const float* src = Af + (size_t)(m0 + arow) * K + k0 + aseg;
        #pragma unroll
        for (int j = 0; j < 16; j += 4) {
          float4 f = *(const float4*)(src + j);
          t.s[j] = f2bf(f.x); t.s[j + 1] = f2bf(f.y);
          t.s[j + 2] = f2bf(f.z); t.s[j + 3] = f2bf(f.w);
        }
      }
      us4* dst = (us4*)&As[arow][aseg];
      dst[0] = t.h[0]; dst[1] = t.h[1]; dst[2] = t.h[2]; dst[3] = t.h[3];
    }
    {  // stage W^T tile 64(n) x 32(k), already bf16
      union { uint4 u; us4 h[2]; } t;
      const unsigned short* src = Wt + (size_t)(n0 + wrow) * K + k0 + wseg;
      t.u = *(const uint4*)src;
      us4* dst = (us4*)&Ws[wrow][wseg];
      dst[0] = t.h[0]; dst[1] = t.h[1];
    }
    __syncthreads();

    bf16x8 af[4], wf[2];
    #pragma unroll
    for (int mi = 0; mi < 4; mi++)
      af[mi] = ld_frag(&As[0][0], wm + mi * 16 + (lane & 15), 36, 0, lane);
    #pragma unroll
    for (int ni = 0; ni < 2; ni++)
      wf[ni] = ld_frag(&Ws[0][0], wn + ni * 16 + (lane & 15), 36, 0, lane);
    #pragma unroll
    for (int mi = 0; mi < 4; mi++)
      #pragma unroll
      for (int ni = 0; ni < 2; ni++)
        acc[mi][ni] = mfma16(af[mi], wf[ni], acc[mi][ni]);
  }

  const float os = p.oscale[z];
  #pragma unroll
  for (int ni = 0; ni < 2; ni++) {
    const int col = n0 + wn + ni * 16 + (lane & 15);
    const float bv = BIAS ? p.bias[z][col] : 0.0f;
    #pragma unroll
    for (int mi = 0; mi < 4; mi++)
      #pragma unroll
      for (int r = 0; r < 4; r++) {
        const int row = m0 + wm + mi * 16 + ((lane >> 4) << 2) + r;
        float vv = (acc[mi][ni][r] + bv) * os;
        if (OBF16) ((unsigned short*)p.C[z])[(size_t)row * N + col] = f2bf(vv);
        else       ((float*)p.C[z])[(size_t)row * N + col] = vv;
      }
  }
}

// ---------------- flash attention, swapped-operand form ----------------
// S^T = K·Q^T  (A=K rows=kv, B=Q cols=q)  ->  C: col(lane&15)=q, row=kv.
// P^T register layout == B-fragment layout for O^T = V^T·P^T  (zero-shuffle PV).
// qh pre-scaled by 1/sqrt(hd). All tensors [B*S][1024] bf16.
__global__ __launch_bounds__(256)
void attn_k2(const unsigned short* __restrict__ qh, const unsigned short* __restrict__ kh,
             const unsigned short* __restrict__ vh, const int* __restrict__ mask,
             unsigned short* __restrict__ ctx) {
  const int S = 2048, DM = 1024;
  __shared__ unsigned short Ks[64][68];   // K tile  [kv][d]
  __shared__ unsigned short VTs[64][68];  // V^T tile [d][kv]
  __shared__ alignas(16) float mkadd[64]; // additive mask per kv
  const int tid = threadIdx.x, lane = tid & 63, w = tid >> 6;
  const int b = blockIdx.z, h = blockIdx.y, q0 = blockIdx.x * 128;
  const int qbase = q0 + w * 32;
  const int lg4 = (lane >> 4) << 2, l15 = lane & 15;

  // Q B-fragments in registers: q = qbase + ni*16 + l15, d = kk*32 + frag-k
  bf16x8 qf[2][2];
  #pragma unroll
  for (int ni = 0; ni < 2; ni++)
    #pragma unroll
    for (int kk = 0; kk < 2; kk++) {
      const unsigned short* p = qh + (size_t)(b * S + qbase + ni * 16 + l15) * DM
                                + h * 64 + kk * 32 + lg4;
      union { bf16x8 f; us4 h4[2]; } u;
      u.h4[0] = *(const us4*)p;
      u.h4[1] = *(const us4*)(p + 16);
      qf[ni][kk] = u.f;
    }

  float mrow[2], lrow[2];
  f32x4 acc_o[4][2] = {};  // O^T: d = mi*16 + 4*(l>>4)+r, q = ni*16 + l15
  mrow[0] = mrow[1] = -1e30f;
  lrow[0] = lrow[1] = 0.f;

  const int srow = tid >> 2, sseg = (tid & 3) * 16;

  for (int kv0 = 0; kv0 < S; kv0 += 64) {
    __syncthreads();
    {
      union { uint4 u[2]; us4 h[4]; unsigned short s[16]; } tk, tv;
      const unsigned short* ksrc = kh + (size_t)(b * S + kv0 + srow) * DM + h * 64 + sseg;
      tk.u[0] = *(const uint4*)ksrc; tk.u[1] = *(const uint4*)(ksrc + 8);
      us4* kd = (us4*)&Ks[srow][sseg];
      kd[0] = tk.h[0]; kd[1] = tk.h[1]; kd[2] = tk.h[2]; kd[3] = tk.h[3];
      const unsigned short* vsrc = vh + (size_t)(b * S + kv0 + srow) * DM + h * 64 + sseg;
      tv.u[0] = *(const uint4*)vsrc; tv.u[1] = *(const uint4*)(vsrc + 8);
      #pragma unroll
      for (int j = 0; j < 16; j++) VTs[sseg + j][srow] = tv.s[j];
      if (tid < 64) mkadd[tid] = (mask[b * S + kv0 + tid] == 0) ? -1e9f : 0.0f;
    }
    __syncthreads();

    // S^T tiles: sc[mi][ni], kv = mi*16 + 4*(l>>4)+r, q = ni*16 + l15
    f32x4 sc[4][2];
    #pragma unroll
    for (int mi = 0; mi < 4; mi++) {
      bf16x8 kf0 = ld_frag(&Ks[0][0], mi * 16 + l15, 68, 0, lane);
      bf16x8 kf1 = ld_frag(&Ks[0][0], mi * 16 + l15, 68, 32, lane);
      #pragma unroll
      for (int ni = 0; ni < 2; ni++) {
        f32x4 zz = {0.f, 0.f, 0.f, 0.f};
        zz = mfma16(kf0, qf[ni][0], zz);
        zz = mfma16(kf1, qf[ni][1], zz);
        sc[mi][ni] = zz;
      }
    }
    // additive mask (broadcast vector reads: 4 floats at kv = mi*16 + 4*(l>>4))
    #pragma unroll
    for (int mi = 0; mi < 4; mi++) {
      f32x4 mv = *(const f32x4*)&mkadd[mi * 16 + lg4];
      #pragma unroll
      for (int ni = 0; ni < 2; ni++) sc[mi][ni] += mv;
    }

    // online softmax per q column (2 shfl for max + 2 for sum, per ni)
    #pragma unroll
    for (int ni = 0; ni < 2; ni++) {
      float pm = sc[0][ni][0];
      #pragma unroll
      for (int mi = 0; mi < 4; mi++)
        #pragma unroll
        for (int r = 0; r < 4; r++) pm = fmaxf(pm, sc[mi][ni][r]);
      pm = fmaxf(pm, __shfl_xor(pm, 16));
      pm = fmaxf(pm, __shfl_xor(pm, 32));
      const float mnew = fmaxf(mrow[ni], pm);
      const float alpha = __expf(mrow[ni] - mnew);
      mrow[ni] = mnew;
      float rs = 0.f;
      #pragma unroll
      for (int mi = 0; mi < 4; mi++)
        #pragma unroll
        for (int r = 0; r < 4; r++) {
          float e = __expf(sc[mi][ni][r] - mnew);
          sc[mi][ni][r] = e;
          rs += e;
        }
      rs += __shfl_xor(rs, 16);
      rs += __shfl_xor(rs, 32);
      lrow[ni] = lrow[ni] * alpha + rs;
      #pragma unroll
      for (int mi = 0; mi < 4; mi++) acc_o[mi][ni] *= alpha;
    }

    // P^T -> bf16 B-fragments, directly from registers (no LDS, no shuffles)
    bf16x8 pb[2][2];
    #pragma unroll
    for (int kc = 0; kc < 2; kc++)
      #pragma unroll
      for (int ni = 0; ni < 2; ni++) {
        bf16x8 f;
        #pragma unroll
        for (int e = 0; e < 8; e++)
          f[e] = (__bf16)sc[2 * kc + (e >> 2)][ni][e & 3];
        pb[kc][ni] = f;
      }

    // O^T += V^T · P^T
    #pragma unroll
    for (int kc = 0; kc < 2; kc++) {
      #pragma unroll
      for (int mi = 0; mi < 4; mi++) {
        bf16x8 va = ld_frag(&VTs[0][0], mi * 16 + l15, 68, kc * 32, lane);
        acc_o[mi][0] = mfma16(va, pb[kc][0], acc_o[mi][0]);
        acc_o[mi][1] = mfma16(va, pb[kc][1], acc_o[mi][1]);
      }
    }
  }

  // epilogue: O^T -> ctx[q][d], packed 8B stores (4 consecutive d per store)
  #pragma unroll
  for (int ni = 0; ni < 2; ni++) {
    const float rinv = 1.0f / lrow[ni];
    const size_t rowoff = (size_t)(b * S + qbase + ni * 16 + l15) * DM + h * 64;
    #pragma unroll
    for (int mi = 0; mi < 4; mi++) {
      us4 o;
      #pragma unroll
      for (int r = 0; r < 4; r++) o[r] = f2bf(acc_o[mi][ni][r] * rinv);
      *(us4*)(ctx + rowoff + mi * 16 + lg4) = o;
    }
  }
}

// ---------------- launch ----------------
extern "C" void kernel_launch(void* const* d_in, const int* in_sizes, int n_in,
                              void* d_out, int out_size, void* d_ws, size_t ws_size,
                              hipStream_t stream) {
  const float* q = (const float*)d_in[0];
  const float* k = (const float*)d_in[1];
  const float* v = (const float*)d_in[2];
  const int* mask = (const int*)d_in[3];
  const float* wu[4] = {(const float*)d_in[4], (const float*)d_in[7],
                        (const float*)d_in[10], (const float*)d_in[13]};
  const float* wv[4] = {(const float*)d_in[5], (const float*)d_in[8],
                        (const float*)d_in[11], (const float*)d_in[14]};
  const float* wb[4] = {(const float*)d_in[6], (const float*)d_in[9],
                        (const float*)d_in[12], (const float*)d_in[15]};

  char* ws = (char*)d_ws;
  unsigned short* WT  = (unsigned short*)ws;                       // 8 * 131072 bf16
  unsigned short* T0  = (unsigned short*)(ws + 2097152);           // 4096x128 bf16
  unsigned short* T1  = T0 + 524288;
  unsigned short* T2  = T1 + 524288;
  unsigned short* QH  = (unsigned short*)(ws + 2097152 + 3145728); // 4096x1024 bf16
  unsigned short* KH  = QH + 4194304;
  unsigned short* VH  = KH + 4194304;
  unsigned short* CTX = VH + 4194304;                              // total ~37 MB

  TP tp;
  for (int i = 0; i < 4; i++) { tp.in[2 * i] = wu[i]; tp.in[2 * i + 1] = wv[i]; }
  for (int i = 0; i < 8; i++) tp.out[i] = WT + (size_t)i * 131072;
  wtrans2<<<dim3(128, 8), 256, 0, stream>>>(tp);

  const float SCALE = 0.125f;  // 1/sqrt(64), folded into qh epilogue

  GP g1 = {};
  g1.A[0] = q; g1.A[1] = k; g1.A[2] = v;
  g1.WT[0] = tp.out[0]; g1.WT[1] = tp.out[2]; g1.WT[2] = tp.out[4];
  g1.C[0] = T0; g1.C[1] = T1; g1.C[2] = T2;
  g1.oscale[0] = g1.oscale[1] = g1.oscale[2] = 1.f;
  gemm_k<false, true, false><<<dim3(32, 2, 3), 256, 0, stream>>>(g1, 4096, 128, 1024);

  GP g2 = {};
  g2.A[0] = T0; g2.A[1] = T1; g2.A[2] = T2;
  g2.WT[0] = tp.out[1]; g2.WT[1] = tp.out[3]; g2.WT[2] = tp.out[5];
  g2.bias[0] = wb[0]; g2.bias[1] = wb[1]; g2.bias[2] = wb[2];
  g2.C[0] = QH; g2.C[1] = KH; g2.C[2] = VH;
  g2.oscale[0] = SCALE; g2.oscale[1] = 1.f; g2.oscale[2] = 1.f;
  gemm_k<true, true, true><<<dim3(32, 16, 3), 256, 0, stream>>>(g2, 4096, 1024, 128);

  attn_k2<<<dim3(16, 16, 2), 256, 0, stream>>>(QH, KH, VH, mask, CTX);

  GP g3 = {};
  g3.A[0] = CTX; g3.WT[0] = tp.out[6]; g3.C[0] = T0; g3.oscale[0] = 1.f;
  gemm_k<true, true, false><<<dim3(32, 2, 1), 256, 0, stream>>>(g3, 4096, 128, 1024);

  GP g4 = {};
  g4.A[0] = T0; g4.WT[0] = tp.out[7]; g4.bias[0] = wb[3];
  g4.C[0] = d_out; g4.oscale[0] = 1.f;
  gemm_k<true, false, true><<<dim3(32, 16, 1), 256, 0, stream>>>(g4, 4096, 1024, 128);
}

// Round 5
// 259.594 us; speedup vs baseline: 1.2288x; 1.0376x over previous
//
#include <hip/hip_runtime.h>
#include <hip/hip_bf16.h>
#include <stdint.h>

#define DEVI __device__ __forceinline__

typedef __attribute__((ext_vector_type(8))) __bf16 bf16x8;
typedef __attribute__((ext_vector_type(4))) float f32x4;
typedef __attribute__((ext_vector_type(4))) unsigned short us4;

DEVI unsigned short f2bf(float x) {
  union { __bf16 b; unsigned short s; } u;
  u.b = (__bf16)x;  // hardware RNE cvt
  return u.s;
}

DEVI f32x4 mfma16(bf16x8 a, bf16x8 b, f32x4 c) {
  return __builtin_amdgcn_mfma_f32_16x16x32_bf16(a, b, c, 0, 0, 0);
}

// Read one 16x32 A/B fragment from a row-major bf16 LDS tile.
// Layout (gfx950 16x16x32): elem e <-> k = 4*(lane>>4) + (e&3) + 16*(e>>2).
DEVI bf16x8 ld_frag(const unsigned short* tile, int row, int ld, int kbase, int lane) {
  const unsigned short* p = tile + row * ld + kbase + ((lane >> 4) << 2);
  union { bf16x8 f; us4 h[2]; } u;
  u.h[0] = *(const us4*)p;
  u.h[1] = *(const us4*)(p + 16);
  return u.f;
}

// ---------------- weight transpose + bf16 cast (tiled, coalesced) ----------------
// even z: u-matrix in [1024][128]; odd z: v-matrix in [128][1024]. out = in^T (bf16).
struct TP { const float* in[8]; unsigned short* out[8]; };

__global__ __launch_bounds__(256) void wtrans2(TP p) {
  const int z = blockIdx.y;
  const int R = (z & 1) ? 128 : 1024;  // in rows
  const int C = (z & 1) ? 1024 : 128;  // in cols; out is [C][R]
  __shared__ unsigned short T[32][33];
  const int tilesC = C >> 5;
  const int tr0 = (blockIdx.x / tilesC) << 5;
  const int tc0 = (blockIdx.x % tilesC) << 5;
  const int tx = threadIdx.x & 31, ty = threadIdx.x >> 5;
  #pragma unroll
  for (int j = 0; j < 4; j++)
    T[ty + j * 8][tx] = f2bf(p.in[z][(size_t)(tr0 + ty + j * 8) * C + tc0 + tx]);
  __syncthreads();
  #pragma unroll
  for (int j = 0; j < 4; j++)
    p.out[z][(size_t)(tc0 + ty + j * 8) * R + tr0 + tx] = T[tx][ty + j * 8];
}

// ---------------- fused low-rank projection ----------------
// Per block: 64 rows of out = (x[64][1024] @ U @ V + bias) * oscale.
// UT = U^T [128][1024] bf16, VT = V^T [1024][128] bf16 (both from wtrans2).
// Phase 1: t[64][128] = x@U  (K=1024, 32-step, 1-deep register prefetch)
// Phase 2: out = t@V        (8 chunks of 128 cols, Ts A-frags hoisted)
struct PJ {
  const void* X[3];
  const unsigned short* UT[3];
  const unsigned short* VT[3];
  const float* bias[3];
  void* O[3];
  float oscale[3];
};

template<bool ABF16, bool OF32>
__global__ __launch_bounds__(256)
void proj_fused(PJ p) {
  // shared layout: phase1 {Xs[64][36], Us[128][36]} aliases phase2 Vs[128][132];
  // Ts[64][132] lives after.
  __shared__ unsigned short SH[128 * 132 + 64 * 132];
  unsigned short* Xs = SH;                 // [64][36]
  unsigned short* Us = SH + 64 * 36;       // [128][36]
  unsigned short* Vs = SH;                 // [128][132]
  unsigned short* Ts = SH + 128 * 132;     // [64][132]

  const int tid = threadIdx.x, lane = tid & 63, w = tid >> 6;
  const int z = blockIdx.z;
  const int m0 = blockIdx.x * 64;
  const int lg4 = (lane >> 4) << 2, l15 = lane & 15;

  const float* Xf = (const float*)p.X[z];
  const unsigned short* Xb = (const unsigned short*)p.X[z];
  const unsigned short* UT = p.UT[z];
  const unsigned short* VT = p.VT[z];

  // staging coords
  const int xr = tid >> 2, xc = (tid & 3) * 8;   // x: 64 rows x 32 cols, 8/thread
  const int ur = tid >> 1, uc = (tid & 1) * 16;  // U^T: 128 rows x 32 cols, 16/thread

  // prefetch regs
  float4 rx0, rx1; uint4 rxb;
  uint4 ru0, ru1;
  auto ldX = [&](int k0) {
    if (ABF16) {
      rxb = *(const uint4*)(Xb + (size_t)(m0 + xr) * 1024 + k0 + xc);
    } else {
      const float* s = Xf + (size_t)(m0 + xr) * 1024 + k0 + xc;
      rx0 = *(const float4*)s; rx1 = *(const float4*)(s + 4);
    }
    const unsigned short* su = UT + (size_t)ur * 1024 + k0 + uc;
    ru0 = *(const uint4*)su; ru1 = *(const uint4*)(su + 8);
  };

  f32x4 acc1[4][2] = {};
  ldX(0);
  for (int k0 = 0; k0 < 1024; k0 += 32) {
    __syncthreads();
    {  // write staged regs to LDS
      union { uint4 u; us4 h[2]; } t;
      us4* xd = (us4*)&Xs[xr * 36 + xc];
      if (ABF16) {
        t.u = rxb; xd[0] = t.h[0]; xd[1] = t.h[1];
      } else {
        us4 a, bq;
        a[0] = f2bf(rx0.x); a[1] = f2bf(rx0.y); a[2] = f2bf(rx0.z); a[3] = f2bf(rx0.w);
        bq[0] = f2bf(rx1.x); bq[1] = f2bf(rx1.y); bq[2] = f2bf(rx1.z); bq[3] = f2bf(rx1.w);
        xd[0] = a; xd[1] = bq;
      }
      us4* udst = (us4*)&Us[ur * 36 + uc];
      t.u = ru0; udst[0] = t.h[0]; udst[1] = t.h[1];
      t.u = ru1; udst[2] = t.h[0]; udst[3] = t.h[1];
    }
    int kn = k0 + 32; if (kn > 992) kn = 992;
    ldX(kn);  // overlap next-tile loads with this tile's MFMAs
    __syncthreads();

    bf16x8 af[4], wf[2];
    #pragma unroll
    for (int mi = 0; mi < 4; mi++)
      af[mi] = ld_frag(Xs, mi * 16 + l15, 36, 0, lane);
    #pragma unroll
    for (int ni = 0; ni < 2; ni++)
      wf[ni] = ld_frag(Us, w * 32 + ni * 16 + l15, 36, 0, lane);
    #pragma unroll
    for (int mi = 0; mi < 4; mi++)
      #pragma unroll
      for (int ni = 0; ni < 2; ni++)
        acc1[mi][ni] = mfma16(af[mi], wf[ni], acc1[mi][ni]);
  }

  // t -> LDS row-major [64 m][132] (single bf16 rounding, as before)
  #pragma unroll
  for (int mi = 0; mi < 4; mi++)
    #pragma unroll
    for (int ni = 0; ni < 2; ni++)
      #pragma unroll
      for (int r = 0; r < 4; r++)
        Ts[(mi * 16 + lg4 + r) * 132 + w * 32 + ni * 16 + l15] = f2bf(acc1[mi][ni][r]);
  __syncthreads();

  // hoist A-frags of t (reused across all 8 output chunks)
  bf16x8 af2[4][4];
  #pragma unroll
  for (int mi = 0; mi < 4; mi++)
    #pragma unroll
    for (int kc = 0; kc < 4; kc++)
      af2[mi][kc] = ld_frag(Ts, mi * 16 + l15, 132, kc * 32, lane);

  const float os = p.oscale[z];
  const int vr = tid >> 2, vc = (tid & 3) * 32;  // Vs staging: 2 passes of 64 rows
  for (int nc = 0; nc < 8; nc++) {
    __syncthreads();  // Vs free (prev chunk frags consumed; first iter: Xs/Us dead)
    #pragma unroll
    for (int pp = 0; pp < 2; pp++) {
      const unsigned short* s = VT + (size_t)(nc * 128 + pp * 64 + vr) * 128 + vc;
      uint4* d = (uint4*)&Vs[(pp * 64 + vr) * 132 + vc];
      #pragma unroll
      for (int j = 0; j < 4; j++) d[j] = *(const uint4*)(s + j * 8);
    }
    __syncthreads();

    f32x4 acc2[4][2] = {};
    #pragma unroll
    for (int kc = 0; kc < 4; kc++) {
      bf16x8 bf0 = ld_frag(Vs, w * 32 + 0 * 16 + l15, 132, kc * 32, lane);
      bf16x8 bf1 = ld_frag(Vs, w * 32 + 1 * 16 + l15, 132, kc * 32, lane);
      #pragma unroll
      for (int mi = 0; mi < 4; mi++) {
        acc2[mi][0] = mfma16(af2[mi][kc], bf0, acc2[mi][0]);
        acc2[mi][1] = mfma16(af2[mi][kc], bf1, acc2[mi][1]);
      }
    }

    #pragma unroll
    for (int ni = 0; ni < 2; ni++) {
      const int col = nc * 128 + w * 32 + ni * 16 + l15;
      const float bv = p.bias[z][col];
      #pragma unroll
      for (int mi = 0; mi < 4; mi++)
        #pragma unroll
        for (int r = 0; r < 4; r++) {
          const int row = m0 + mi * 16 + lg4 + r;
          float vv = (acc2[mi][ni][r] + bv) * os;
          if (OF32) ((float*)p.O[z])[(size_t)row * 1024 + col] = vv;
          else ((unsigned short*)p.O[z])[(size_t)row * 1024 + col] = f2bf(vv);
        }
    }
  }
}

// ---------------- flash attention, swapped-operand + 1-deep K/V prefetch ----------
// S^T = K·Q^T; P^T regs == B-frag layout for O^T = V^T·P^T (zero-shuffle PV).
__global__ __launch_bounds__(256)
void attn_k2p(const unsigned short* __restrict__ qh, const unsigned short* __restrict__ kh,
              const unsigned short* __restrict__ vh, const int* __restrict__ mask,
              unsigned short* __restrict__ ctx) {
  const int S = 2048, DM = 1024;
  __shared__ unsigned short Ks[64][68];   // K tile  [kv][d]
  __shared__ unsigned short VTs[64][68];  // V^T tile [d][kv]
  __shared__ alignas(16) float mkadd[64];
  const int tid = threadIdx.x, lane = tid & 63, w = tid >> 6;
  const int b = blockIdx.z, h = blockIdx.y, q0 = blockIdx.x * 128;
  const int qbase = q0 + w * 32;
  const int lg4 = (lane >> 4) << 2, l15 = lane & 15;

  bf16x8 qf[2][2];
  #pragma unroll
  for (int ni = 0; ni < 2; ni++)
    #pragma unroll
    for (int kk = 0; kk < 2; kk++) {
      const unsigned short* p = qh + (size_t)(b * S + qbase + ni * 16 + l15) * DM
                                + h * 64 + kk * 32 + lg4;
      union { bf16x8 f; us4 h4[2]; } u;
      u.h4[0] = *(const us4*)p;
      u.h4[1] = *(const us4*)(p + 16);
      qf[ni][kk] = u.f;
    }

  float mrow[2], lrow[2];
  f32x4 acc_o[4][2] = {};
  mrow[0] = mrow[1] = -1e30f;
  lrow[0] = lrow[1] = 0.f;

  const int srow = tid >> 2, sseg = (tid & 3) * 16;

  // prefetch regs
  uint4 rk0, rk1, rv0, rv1; int rmI = 1;
  auto ldT = [&](int kv0) {
    const unsigned short* ksrc = kh + (size_t)(b * S + kv0 + srow) * DM + h * 64 + sseg;
    rk0 = *(const uint4*)ksrc; rk1 = *(const uint4*)(ksrc + 8);
    const unsigned short* vsrc = vh + (size_t)(b * S + kv0 + srow) * DM + h * 64 + sseg;
    rv0 = *(const uint4*)vsrc; rv1 = *(const uint4*)(vsrc + 8);
    if (tid < 64) rmI = mask[b * S + kv0 + tid];
  };
  ldT(0);

  for (int kv0 = 0; kv0 < S; kv0 += 64) {
    __syncthreads();
    {  // LDS writes from prefetched regs
      union { uint4 u[2]; unsigned short s[16]; us4 h[4]; } tk, tv;
      tk.u[0] = rk0; tk.u[1] = rk1;
      us4* kd = (us4*)&Ks[srow][sseg];
      kd[0] = tk.h[0]; kd[1] = tk.h[1]; kd[2] = tk.h[2]; kd[3] = tk.h[3];
      tv.u[0] = rv0; tv.u[1] = rv1;
      #pragma unroll
      for (int j = 0; j < 16; j++) VTs[sseg + j][srow] = tv.s[j];
      if (tid < 64) mkadd[tid] = (rmI == 0) ? -1e9f : 0.0f;
    }
    int nxt = kv0 + 64; if (nxt >= S) nxt = kv0;
    ldT(nxt);  // overlap next-tile loads with compute
    __syncthreads();

    // S^T tiles: kv = mi*16 + lg4 + r, q = ni*16 + l15
    f32x4 sc[4][2];
    #pragma unroll
    for (int mi = 0; mi < 4; mi++) {
      bf16x8 kf0 = ld_frag(&Ks[0][0], mi * 16 + l15, 68, 0, lane);
      bf16x8 kf1 = ld_frag(&Ks[0][0], mi * 16 + l15, 68, 32, lane);
      #pragma unroll
      for (int ni = 0; ni < 2; ni++) {
        f32x4 zz = {0.f, 0.f, 0.f, 0.f};
        zz = mfma16(kf0, qf[ni][0], zz);
        zz = mfma16(kf1, qf[ni][1], zz);
        sc[mi][ni] = zz;
      }
    }
    #pragma unroll
    for (int mi = 0; mi < 4; mi++) {
      f32x4 mv = *(const f32x4*)&mkadd[mi * 16 + lg4];
      #pragma unroll
      for (int ni = 0; ni < 2; ni++) sc[mi][ni] += mv;
    }

    // online softmax per q column
    #pragma unroll
    for (int ni = 0; ni < 2; ni++) {
      float pm = sc[0][ni][0];
      #pragma unroll
      for (int mi = 0; mi < 4; mi++)
        #pragma unroll
        for (int r = 0; r < 4; r++) pm = fmaxf(pm, sc[mi][ni][r]);
      pm = fmaxf(pm, __shfl_xor(pm, 16));
      pm = fmaxf(pm, __shfl_xor(pm, 32));
      const float mnew = fmaxf(mrow[ni], pm);
      const float alpha = __expf(mrow[ni] - mnew);
      mrow[ni] = mnew;
      float rs = 0.f;
      #pragma unroll
      for (int mi = 0; mi < 4; mi++)
        #pragma unroll
        for (int r = 0; r < 4; r++) {
          float e = __expf(sc[mi][ni][r] - mnew);
          sc[mi][ni][r] = e;
          rs += e;
        }
      rs += __shfl_xor(rs, 16);
      rs += __shfl_xor(rs, 32);
      lrow[ni] = lrow[ni] * alpha + rs;
      #pragma unroll
      for (int mi = 0; mi < 4; mi++) acc_o[mi][ni] *= alpha;
    }

    // P^T -> bf16 B-fragments directly in registers
    bf16x8 pb[2][2];
    #pragma unroll
    for (int kc = 0; kc < 2; kc++)
      #pragma unroll
      for (int ni = 0; ni < 2; ni++) {
        bf16x8 f;
        #pragma unroll
        for (int e = 0; e < 8; e++)
          f[e] = (__bf16)sc[2 * kc + (e >> 2)][ni][e & 3];
        pb[kc][ni] = f;
      }

    // O^T += V^T · P^T
    #pragma unroll
    for (int kc = 0; kc < 2; kc++) {
      #pragma unroll
      for (int mi = 0; mi < 4; mi++) {
        bf16x8 va = ld_frag(&VTs[0][0], mi * 16 + l15, 68, kc * 32, lane);
        acc_o[mi][0] = mfma16(va, pb[kc][0], acc_o[mi][0]);
        acc_o[mi][1] = mfma16(va, pb[kc][1], acc_o[mi][1]);
      }
    }
  }

  #pragma unroll
  for (int ni = 0; ni < 2; ni++) {
    const float rinv = 1.0f / lrow[ni];
    const size_t rowoff = (size_t)(b * S + qbase + ni * 16 + l15) * DM + h * 64;
    #pragma unroll
    for (int mi = 0; mi < 4; mi++) {
      us4 o;
      #pragma unroll
      for (int r = 0; r < 4; r++) o[r] = f2bf(acc_o[mi][ni][r] * rinv);
      *(us4*)(ctx + rowoff + mi * 16 + lg4) = o;
    }
  }
}

// ---------------- launch ----------------
extern "C" void kernel_launch(void* const* d_in, const int* in_sizes, int n_in,
                              void* d_out, int out_size, void* d_ws, size_t ws_size,
                              hipStream_t stream) {
  const float* q = (const float*)d_in[0];
  const float* k = (const float*)d_in[1];
  const float* v = (const float*)d_in[2];
  const int* mask = (const int*)d_in[3];
  const float* wu[4] = {(const float*)d_in[4], (const float*)d_in[7],
                        (const float*)d_in[10], (const float*)d_in[13]};
  const float* wv[4] = {(const float*)d_in[5], (const float*)d_in[8],
                        (const float*)d_in[11], (const float*)d_in[14]};
  const float* wb[4] = {(const float*)d_in[6], (const float*)d_in[9],
                        (const float*)d_in[12], (const float*)d_in[15]};

  char* ws = (char*)d_ws;
  unsigned short* WT  = (unsigned short*)ws;              // 8 * 131072 bf16 = 2MB
  unsigned short* QH  = (unsigned short*)(ws + 2097152);  // 4096x1024 bf16 each
  unsigned short* KH  = QH + 4194304;
  unsigned short* VH  = KH + 4194304;
  unsigned short* CTX = VH + 4194304;                     // total ~34MB

  TP tp;
  for (int i = 0; i < 4; i++) { tp.in[2 * i] = wu[i]; tp.in[2 * i + 1] = wv[i]; }
  for (int i = 0; i < 8; i++) tp.out[i] = WT + (size_t)i * 131072;
  wtrans2<<<dim3(128, 8), 256, 0, stream>>>(tp);

  const float SCALE = 0.125f;  // 1/sqrt(64), folded into qh

  PJ pq = {};
  pq.X[0] = q; pq.X[1] = k; pq.X[2] = v;
  pq.UT[0] = tp.out[0]; pq.UT[1] = tp.out[2]; pq.UT[2] = tp.out[4];
  pq.VT[0] = tp.out[1]; pq.VT[1] = tp.out[3]; pq.VT[2] = tp.out[5];
  pq.bias[0] = wb[0]; pq.bias[1] = wb[1]; pq.bias[2] = wb[2];
  pq.O[0] = QH; pq.O[1] = KH; pq.O[2] = VH;
  pq.oscale[0] = SCALE; pq.oscale[1] = 1.f; pq.oscale[2] = 1.f;
  proj_fused<false, false><<<dim3(64, 1, 3), 256, 0, stream>>>(pq);

  attn_k2p<<<dim3(16, 16, 2), 256, 0, stream>>>(QH, KH, VH, mask, CTX);

  PJ po = {};
  po.X[0] = CTX;
  po.UT[0] = tp.out[6];
  po.VT[0] = tp.out[7];
  po.bias[0] = wb[3];
  po.O[0] = d_out;
  po.oscale[0] = 1.f;
  proj_fused<true, true><<<dim3(64, 1, 1), 256, 0, stream>>>(po);
}

// Round 6
// 256.772 us; speedup vs baseline: 1.2423x; 1.0110x over previous
//
#include <hip/hip_runtime.h>
#include <hip/hip_bf16.h>
#include <stdint.h>

#define DEVI __device__ __forceinline__

typedef __attribute__((ext_vector_type(8))) __bf16 bf16x8;
typedef __attribute__((ext_vector_type(4))) float f32x4;
typedef __attribute__((ext_vector_type(4))) unsigned short us4;

DEVI unsigned short f2bf(float x) {
  union { __bf16 b; unsigned short s; } u;
  u.b = (__bf16)x;  // hardware RNE cvt
  return u.s;
}

DEVI f32x4 mfma16(bf16x8 a, bf16x8 b, f32x4 c) {
  return __builtin_amdgcn_mfma_f32_16x16x32_bf16(a, b, c, 0, 0, 0);
}

DEVI f32x4 vmax4(f32x4 a, f32x4 b) {
  f32x4 r;
  r[0] = fmaxf(a[0], b[0]); r[1] = fmaxf(a[1], b[1]);
  r[2] = fmaxf(a[2], b[2]); r[3] = fmaxf(a[3], b[3]);
  return r;
}

// Read one 16x32 A/B fragment from a row-major bf16 LDS tile.
// Layout (gfx950 16x16x32): elem e <-> k = 4*(lane>>4) + (e&3) + 16*(e>>2).
DEVI bf16x8 ld_frag(const unsigned short* tile, int row, int ld, int kbase, int lane) {
  const unsigned short* p = tile + row * ld + kbase + ((lane >> 4) << 2);
  union { bf16x8 f; us4 h[2]; } u;
  u.h[0] = *(const us4*)p;
  u.h[1] = *(const us4*)(p + 16);
  return u.f;
}

// ---------------- weight transpose + bf16 cast (tiled, coalesced) ----------------
struct TP { const float* in[8]; unsigned short* out[8]; };

__global__ __launch_bounds__(256) void wtrans2(TP p) {
  const int z = blockIdx.y;
  const int R = (z & 1) ? 128 : 1024;  // in rows
  const int C = (z & 1) ? 1024 : 128;  // in cols; out is [C][R]
  __shared__ unsigned short T[32][33];
  const int tilesC = C >> 5;
  const int tr0 = (blockIdx.x / tilesC) << 5;
  const int tc0 = (blockIdx.x % tilesC) << 5;
  const int tx = threadIdx.x & 31, ty = threadIdx.x >> 5;
  #pragma unroll
  for (int j = 0; j < 4; j++)
    T[ty + j * 8][tx] = f2bf(p.in[z][(size_t)(tr0 + ty + j * 8) * C + tc0 + tx]);
  __syncthreads();
  #pragma unroll
  for (int j = 0; j < 4; j++)
    p.out[z][(size_t)(tc0 + ty + j * 8) * R + tr0 + tx] = T[tx][ty + j * 8];
}

// ---------------- fused low-rank projection ----------------
struct PJ {
  const void* X[3];
  const unsigned short* UT[3];
  const unsigned short* VT[3];
  const float* bias[3];
  void* O[3];
  float oscale[3];
};

template<bool ABF16, bool OF32>
__global__ __launch_bounds__(256)
void proj_fused(PJ p) {
  __shared__ unsigned short SH[128 * 132 + 64 * 132];
  unsigned short* Xs = SH;                 // [64][36]
  unsigned short* Us = SH + 64 * 36;       // [128][36]
  unsigned short* Vs = SH;                 // [128][132]
  unsigned short* Ts = SH + 128 * 132;     // [64][132]

  const int tid = threadIdx.x, lane = tid & 63, w = tid >> 6;
  const int z = blockIdx.z;
  const int m0 = blockIdx.x * 64;
  const int lg4 = (lane >> 4) << 2, l15 = lane & 15;

  const float* Xf = (const float*)p.X[z];
  const unsigned short* Xb = (const unsigned short*)p.X[z];
  const unsigned short* UT = p.UT[z];
  const unsigned short* VT = p.VT[z];

  const int xr = tid >> 2, xc = (tid & 3) * 8;
  const int ur = tid >> 1, uc = (tid & 1) * 16;

  float4 rx0, rx1; uint4 rxb;
  uint4 ru0, ru1;
  auto ldX = [&](int k0) {
    if (ABF16) {
      rxb = *(const uint4*)(Xb + (size_t)(m0 + xr) * 1024 + k0 + xc);
    } else {
      const float* s = Xf + (size_t)(m0 + xr) * 1024 + k0 + xc;
      rx0 = *(const float4*)s; rx1 = *(const float4*)(s + 4);
    }
    const unsigned short* su = UT + (size_t)ur * 1024 + k0 + uc;
    ru0 = *(const uint4*)su; ru1 = *(const uint4*)(su + 8);
  };

  f32x4 acc1[4][2] = {};
  ldX(0);
  for (int k0 = 0; k0 < 1024; k0 += 32) {
    __syncthreads();
    {
      union { uint4 u; us4 h[2]; } t;
      us4* xd = (us4*)&Xs[xr * 36 + xc];
      if (ABF16) {
        t.u = rxb; xd[0] = t.h[0]; xd[1] = t.h[1];
      } else {
        us4 a, bq;
        a[0] = f2bf(rx0.x); a[1] = f2bf(rx0.y); a[2] = f2bf(rx0.z); a[3] = f2bf(rx0.w);
        bq[0] = f2bf(rx1.x); bq[1] = f2bf(rx1.y); bq[2] = f2bf(rx1.z); bq[3] = f2bf(rx1.w);
        xd[0] = a; xd[1] = bq;
      }
      us4* udst = (us4*)&Us[ur * 36 + uc];
      t.u = ru0; udst[0] = t.h[0]; udst[1] = t.h[1];
      t.u = ru1; udst[2] = t.h[0]; udst[3] = t.h[1];
    }
    int kn = k0 + 32; if (kn > 992) kn = 992;
    ldX(kn);
    __syncthreads();

    bf16x8 af[4], wf[2];
    #pragma unroll
    for (int mi = 0; mi < 4; mi++)
      af[mi] = ld_frag(Xs, mi * 16 + l15, 36, 0, lane);
    #pragma unroll
    for (int ni = 0; ni < 2; ni++)
      wf[ni] = ld_frag(Us, w * 32 + ni * 16 + l15, 36, 0, lane);
    #pragma unroll
    for (int mi = 0; mi < 4; mi++)
      #pragma unroll
      for (int ni = 0; ni < 2; ni++)
        acc1[mi][ni] = mfma16(af[mi], wf[ni], acc1[mi][ni]);
  }

  #pragma unroll
  for (int mi = 0; mi < 4; mi++)
    #pragma unroll
    for (int ni = 0; ni < 2; ni++)
      #pragma unroll
      for (int r = 0; r < 4; r++)
        Ts[(mi * 16 + lg4 + r) * 132 + w * 32 + ni * 16 + l15] = f2bf(acc1[mi][ni][r]);
  __syncthreads();

  bf16x8 af2[4][4];
  #pragma unroll
  for (int mi = 0; mi < 4; mi++)
    #pragma unroll
    for (int kc = 0; kc < 4; kc++)
      af2[mi][kc] = ld_frag(Ts, mi * 16 + l15, 132, kc * 32, lane);

  const float os = p.oscale[z];
  const int vr = tid >> 2, vc = (tid & 3) * 32;
  for (int nc = 0; nc < 8; nc++) {
    __syncthreads();
    #pragma unroll
    for (int pp = 0; pp < 2; pp++) {
      const unsigned short* s = VT + (size_t)(nc * 128 + pp * 64 + vr) * 128 + vc;
      uint4* d = (uint4*)&Vs[(pp * 64 + vr) * 132 + vc];
      #pragma unroll
      for (int j = 0; j < 4; j++) d[j] = *(const uint4*)(s + j * 8);
    }
    __syncthreads();

    f32x4 acc2[4][2] = {};
    #pragma unroll
    for (int kc = 0; kc < 4; kc++) {
      bf16x8 bf0 = ld_frag(Vs, w * 32 + 0 * 16 + l15, 132, kc * 32, lane);
      bf16x8 bf1 = ld_frag(Vs, w * 32 + 1 * 16 + l15, 132, kc * 32, lane);
      #pragma unroll
      for (int mi = 0; mi < 4; mi++) {
        acc2[mi][0] = mfma16(af2[mi][kc], bf0, acc2[mi][0]);
        acc2[mi][1] = mfma16(af2[mi][kc], bf1, acc2[mi][1]);
      }
    }

    #pragma unroll
    for (int ni = 0; ni < 2; ni++) {
      const int col = nc * 128 + w * 32 + ni * 16 + l15;
      const float bv = p.bias[z][col];
      #pragma unroll
      for (int mi = 0; mi < 4; mi++)
        #pragma unroll
        for (int r = 0; r < 4; r++) {
          const int row = m0 + mi * 16 + lg4 + r;
          float vv = (acc2[mi][ni][r] + bv) * os;
          if (OF32) ((float*)p.O[z])[(size_t)row * 1024 + col] = vv;
          else ((unsigned short*)p.O[z])[(size_t)row * 1024 + col] = f2bf(vv);
        }
    }
  }
}

// ---------------- flash attention v3: 8 waves x 16 q-rows, tree softmax, defer-max
// S^T = K·Q^T; P^T regs == B-frag layout for O^T = V^T·P^T (zero-shuffle PV).
__global__ __launch_bounds__(512, 4)
void attn_k3(const unsigned short* __restrict__ qh, const unsigned short* __restrict__ kh,
             const unsigned short* __restrict__ vh, const int* __restrict__ mask,
             unsigned short* __restrict__ ctx) {
  const int S = 2048, DM = 1024;
  __shared__ unsigned short Ks[64][68];   // K tile  [kv][d]
  __shared__ unsigned short VTs[64][68];  // V^T tile [d][kv]
  __shared__ alignas(16) float mkadd[64];
  const int tid = threadIdx.x, lane = tid & 63, w = tid >> 6;  // 8 waves
  const int b = blockIdx.z, h = blockIdx.y, q0 = blockIdx.x * 128;
  const int lg4 = (lane >> 4) << 2, l15 = lane & 15;
  const int qrow = q0 + w * 16 + l15;  // this lane's q row (16 rows per wave)

  // Q B-fragments (one 16-col group per wave)
  bf16x8 qf[2];
  #pragma unroll
  for (int kk = 0; kk < 2; kk++) {
    const unsigned short* p = qh + (size_t)(b * S + qrow) * DM + h * 64 + kk * 32 + lg4;
    union { bf16x8 f; us4 h4[2]; } u;
    u.h4[0] = *(const us4*)p;
    u.h4[1] = *(const us4*)(p + 16);
    qf[kk] = u.f;
  }

  float mrow = -1e30f, lrow = 0.f;
  f32x4 acc_o[4] = {};  // O^T: d = mi*16 + lg4 + r, q = qrow

  const int srow = tid >> 3, sseg = (tid & 7) * 8;  // 512 thr: 8 shorts each

  uint4 rk, rv; int rmI = 1;
  auto ldT = [&](int kv0) {
    rk = *(const uint4*)(kh + (size_t)(b * S + kv0 + srow) * DM + h * 64 + sseg);
    rv = *(const uint4*)(vh + (size_t)(b * S + kv0 + srow) * DM + h * 64 + sseg);
    if (tid < 64) rmI = mask[b * S + kv0 + tid];
  };
  ldT(0);

  for (int kv0 = 0; kv0 < S; kv0 += 64) {
    __syncthreads();
    {
      union { uint4 u; us4 h[2]; unsigned short s[8]; } tk, tv;
      tk.u = rk;
      us4* kd = (us4*)&Ks[srow][sseg];
      kd[0] = tk.h[0]; kd[1] = tk.h[1];
      tv.u = rv;
      #pragma unroll
      for (int j = 0; j < 8; j++) VTs[sseg + j][srow] = tv.s[j];
      if (tid < 64) mkadd[tid] = (rmI == 0) ? -1e9f : 0.0f;
    }
    int nxt = kv0 + 64; if (nxt >= S) nxt = kv0;
    ldT(nxt);  // overlap next-tile loads with compute
    __syncthreads();

    // S^T: kv = mi*16 + lg4 + r, q = qrow
    f32x4 sc[4];
    __builtin_amdgcn_s_setprio(1);
    #pragma unroll
    for (int mi = 0; mi < 4; mi++) {
      bf16x8 kf0 = ld_frag(&Ks[0][0], mi * 16 + l15, 68, 0, lane);
      bf16x8 kf1 = ld_frag(&Ks[0][0], mi * 16 + l15, 68, 32, lane);
      f32x4 zz = {0.f, 0.f, 0.f, 0.f};
      zz = mfma16(kf0, qf[0], zz);
      zz = mfma16(kf1, qf[1], zz);
      sc[mi] = zz;
    }
    __builtin_amdgcn_s_setprio(0);
    #pragma unroll
    for (int mi = 0; mi < 4; mi++)
      sc[mi] += *(const f32x4*)&mkadd[mi * 16 + lg4];

    // tree max (depth 4 + 2 shfl)
    f32x4 tm = vmax4(vmax4(sc[0], sc[1]), vmax4(sc[2], sc[3]));
    float pm = fmaxf(fmaxf(tm[0], tm[1]), fmaxf(tm[2], tm[3]));
    pm = fmaxf(pm, __shfl_xor(pm, 16));
    pm = fmaxf(pm, __shfl_xor(pm, 32));

    // defer-max: only rescale when the running max grew by > 8
    if (!__all(pm <= mrow + 8.f)) {
      const float mnew = fmaxf(mrow, pm);
      const float alpha = __expf(mrow - mnew);
      lrow *= alpha;
      #pragma unroll
      for (int mi = 0; mi < 4; mi++) acc_o[mi] *= alpha;
      mrow = mnew;
    }

    #pragma unroll
    for (int mi = 0; mi < 4; mi++)
      #pragma unroll
      for (int r = 0; r < 4; r++)
        sc[mi][r] = __expf(sc[mi][r] - mrow);

    f32x4 ssum = (sc[0] + sc[1]) + (sc[2] + sc[3]);
    float rs = (ssum[0] + ssum[1]) + (ssum[2] + ssum[3]);
    rs += __shfl_xor(rs, 16);
    rs += __shfl_xor(rs, 32);
    lrow += rs;

    // P^T -> bf16 B-fragments directly in registers
    bf16x8 pb[2];
    #pragma unroll
    for (int kc = 0; kc < 2; kc++) {
      bf16x8 f;
      #pragma unroll
      for (int e = 0; e < 8; e++)
        f[e] = (__bf16)sc[2 * kc + (e >> 2)][e & 3];
      pb[kc] = f;
    }

    // O^T += V^T · P^T
    __builtin_amdgcn_s_setprio(1);
    #pragma unroll
    for (int kc = 0; kc < 2; kc++)
      #pragma unroll
      for (int mi = 0; mi < 4; mi++) {
        bf16x8 va = ld_frag(&VTs[0][0], mi * 16 + l15, 68, kc * 32, lane);
        acc_o[mi] = mfma16(va, pb[kc], acc_o[mi]);
      }
    __builtin_amdgcn_s_setprio(0);
  }

  const float rinv = 1.0f / lrow;
  const size_t rowoff = (size_t)(b * S + qrow) * DM + h * 64;
  #pragma unroll
  for (int mi = 0; mi < 4; mi++) {
    us4 o;
    #pragma unroll
    for (int r = 0; r < 4; r++) o[r] = f2bf(acc_o[mi][r] * rinv);
    *(us4*)(ctx + rowoff + mi * 16 + lg4) = o;
  }
}

// ---------------- launch ----------------
extern "C" void kernel_launch(void* const* d_in, const int* in_sizes, int n_in,
                              void* d_out, int out_size, void* d_ws, size_t ws_size,
                              hipStream_t stream) {
  const float* q = (const float*)d_in[0];
  const float* k = (const float*)d_in[1];
  const float* v = (const float*)d_in[2];
  const int* mask = (const int*)d_in[3];
  const float* wu[4] = {(const float*)d_in[4], (const float*)d_in[7],
                        (const float*)d_in[10], (const float*)d_in[13]};
  const float* wv[4] = {(const float*)d_in[5], (const float*)d_in[8],
                        (const float*)d_in[11], (const float*)d_in[14]};
  const float* wb[4] = {(const float*)d_in[6], (const float*)d_in[9],
                        (const float*)d_in[12], (const float*)d_in[15]};

  char* ws = (char*)d_ws;
  unsigned short* WT  = (unsigned short*)ws;              // 8 * 131072 bf16 = 2MB
  unsigned short* QH  = (unsigned short*)(ws + 2097152);  // 4096x1024 bf16 each
  unsigned short* KH  = QH + 4194304;
  unsigned short* VH  = KH + 4194304;
  unsigned short* CTX = VH + 4194304;                     // total ~34MB

  TP tp;
  for (int i = 0; i < 4; i++) { tp.in[2 * i] = wu[i]; tp.in[2 * i + 1] = wv[i]; }
  for (int i = 0; i < 8; i++) tp.out[i] = WT + (size_t)i * 131072;
  wtrans2<<<dim3(128, 8), 256, 0, stream>>>(tp);

  const float SCALE = 0.125f;  // 1/sqrt(64), folded into qh

  PJ pq = {};
  pq.X[0] = q; pq.X[1] = k; pq.X[2] = v;
  pq.UT[0] = tp.out[0]; pq.UT[1] = tp.out[2]; pq.UT[2] = tp.out[4];
  pq.VT[0] = tp.out[1]; pq.VT[1] = tp.out[3]; pq.VT[2] = tp.out[5];
  pq.bias[0] = wb[0]; pq.bias[1] = wb[1]; pq.bias[2] = wb[2];
  pq.O[0] = QH; pq.O[1] = KH; pq.O[2] = VH;
  pq.oscale[0] = SCALE; pq.oscale[1] = 1.f; pq.oscale[2] = 1.f;
  proj_fused<false, false><<<dim3(64, 1, 3), 256, 0, stream>>>(pq);

  attn_k3<<<dim3(16, 16, 2), 512, 0, stream>>>(QH, KH, VH, mask, CTX);

  PJ po = {};
  po.X[0] = CTX;
  po.UT[0] = tp.out[6];
  po.VT[0] = tp.out[7];
  po.bias[0] = wb[3];
  po.O[0] = d_out;
  po.oscale[0] = 1.f;
  proj_fused<true, true><<<dim3(64, 1, 1), 256, 0, stream>>>(po);
}